// Round 1
// baseline (261.108 us; speedup 1.0000x reference)
//
#include <hip/hip_runtime.h>
#include <hip/hip_bf16.h>

// L=256, B=32, H=8, d_head=64, m=256, feature dim 2m=512, D_MODEL=512
#define L_SEQ 256
#define B_SZ  32
#define NH    8
#define DH    64
#define DM    512
#define FD    512
#define PM    256
#define ROWS  8192
#define QKVN  2048

typedef __bf16 bf16x8 __attribute__((ext_vector_type(8)));
typedef float f32x4 __attribute__((ext_vector_type(4)));
#define MFMA16(a, b, c) __builtin_amdgcn_mfma_f32_16x16x32_bf16((a), (b), (c), 0, 0, 0)

static __device__ __forceinline__ void stmix(void* p, long i, float v, int f32) {
  if (f32) ((float*)p)[i] = v;
  else     ((__bf16*)p)[i] = (__bf16)v;
}

// ---------------------------------------------------------------------------
// P0: prep — probe + h-cvt + 3 transposes + tiny cvts in one launch
// (validated rounds 7-8). Every block re-derives the dtype flag inline.
// ---------------------------------------------------------------------------
#define PREP_HB   2048
#define PREP_WT   256
#define PREP_WOT  64
#define PREP_PJ   4
#define PREP_TINY 1
#define PREP_BLOCKS (PREP_HB + PREP_WT + PREP_WOT + PREP_PJ + PREP_TINY)

__global__ __launch_bounds__(256) void prep(
    const void* __restrict__ h, const void* __restrict__ wqkv,
    const void* __restrict__ wo, const void* __restrict__ proj,
    const void* __restrict__ pi0, const void* __restrict__ pi1,
    const void* __restrict__ gam, const void* __restrict__ bet,
    int* __restrict__ flag, __bf16* __restrict__ hb, __bf16* __restrict__ wt,
    __bf16* __restrict__ wot, __bf16* __restrict__ projT,
    __bf16* __restrict__ pi0b, __bf16* __restrict__ pi1b,
    __bf16* __restrict__ gamb, __bf16* __restrict__ betb) {
  __shared__ float T[64][69];
  __shared__ int red[256];
  const int tid = threadIdx.x;
  int cnt = 0;
  {
    const unsigned short* hbits = (const unsigned short*)h;
    for (int i = 0; i < 16; ++i) {
      const unsigned short u = hbits[tid * 16 + i];
      if (((u >> 7) & 0xFF) >= 0xA0) ++cnt;
    }
  }
  red[tid] = cnt; __syncthreads();
  for (int s = 128; s > 0; s >>= 1) { if (tid < s) red[tid] += red[tid + s]; __syncthreads(); }
  const int f32 = (red[0] >= 64) ? 1 : 0;
  __syncthreads();

  const int blk = blockIdx.x;
  if (blk < PREP_HB) {
    const int i = blk * 256 + tid;
    if (f32) {
      const f32x4* s = (const f32x4*)h;
      const f32x4 a = s[i * 2], b = s[i * 2 + 1];
      bf16x8 t;
      t[0] = (__bf16)a[0]; t[1] = (__bf16)a[1]; t[2] = (__bf16)a[2]; t[3] = (__bf16)a[3];
      t[4] = (__bf16)b[0]; t[5] = (__bf16)b[1]; t[6] = (__bf16)b[2]; t[7] = (__bf16)b[3];
      *reinterpret_cast<bf16x8*>(hb + (long)i * 8) = t;
    } else {
      *reinterpret_cast<bf16x8*>(hb + (long)i * 8) = ((const bf16x8*)h)[i];
    }
    return;
  }
  const void* src; __bf16* dst; int M, N, n0, m0;
  if (blk < PREP_HB + PREP_WT) {
    const int x = blk - PREP_HB;
    src = wqkv; dst = wt; M = 512; N = 2048; n0 = (x & 31) * 64; m0 = (x >> 5) * 64;
  } else if (blk < PREP_HB + PREP_WT + PREP_WOT) {
    const int x = blk - PREP_HB - PREP_WT;
    src = wo; dst = wot; M = 512; N = 512; n0 = (x & 7) * 64; m0 = (x >> 3) * 64;
  } else if (blk < PREP_HB + PREP_WT + PREP_WOT + PREP_PJ) {
    const int x = blk - PREP_HB - PREP_WT - PREP_WOT;
    src = proj; dst = projT; M = 64; N = 256; n0 = x * 64; m0 = 0;
  } else {
    if (tid == 0) flag[0] = f32;
    if (f32) {
      const float* s0 = (const float*)pi0; const float* s1 = (const float*)pi1;
      const float* s2 = (const float*)gam; const float* s3 = (const float*)bet;
      for (int i = tid; i < NH * 256; i += 256) { pi0b[i] = (__bf16)s0[i]; pi1b[i] = (__bf16)s1[i]; }
      for (int i = tid; i < DM; i += 256)      { gamb[i] = (__bf16)s2[i]; betb[i] = (__bf16)s3[i]; }
    } else {
      const __bf16* s0 = (const __bf16*)pi0; const __bf16* s1 = (const __bf16*)pi1;
      const __bf16* s2 = (const __bf16*)gam; const __bf16* s3 = (const __bf16*)bet;
      for (int i = tid; i < NH * 256; i += 256) { pi0b[i] = s0[i]; pi1b[i] = s1[i]; }
      for (int i = tid; i < DM; i += 256)      { gamb[i] = s2[i]; betb[i] = s3[i]; }
    }
    return;
  }
  if (f32) {
    const float* s = (const float*)src;
#pragma unroll
    for (int rep = 0; rep < 16; ++rep) {
      const int i = rep * 4 + (tid >> 6), j = tid & 63;
      T[i][j] = s[(long)(m0 + i) * N + n0 + j];
    }
  } else {
    const __bf16* s = (const __bf16*)src;
#pragma unroll
    for (int rep = 0; rep < 16; ++rep) {
      const int i = rep * 4 + (tid >> 6), j = tid & 63;
      T[i][j] = (float)s[(long)(m0 + i) * N + n0 + j];
    }
  }
  __syncthreads();
#pragma unroll
  for (int rep = 0; rep < 16; ++rep) {
    const int i = rep * 4 + (tid >> 6), j = tid & 63;
    dst[(long)(n0 + i) * M + m0 + j] = (__bf16)T[j][i];
  }
}

// ---------------------------------------------------------------------------
// K1: qkv = hb @ w_qkv via MFMA with register prefetch (validated rounds 7-8).
// ---------------------------------------------------------------------------
__global__ __launch_bounds__(256) void gemm_h_wqkv(const __bf16* __restrict__ A,
                                                   const __bf16* __restrict__ Bt,
                                                   __bf16* __restrict__ C) {
  __shared__ __bf16 At[64][136];
  __shared__ __bf16 Bts[64][136];
  const int n0 = blockIdx.x * 64, m0 = blockIdx.y * 64;
  const int tid = threadIdx.x, lane = tid & 63, wv = tid >> 6;
  const int m = lane & 15, q = lane >> 4;
  const int r = tid >> 2, c0 = (tid & 3) * 32;
  const __bf16* ap = A + (long)(m0 + r) * DM + c0;
  const __bf16* bp = Bt + (long)(n0 + r) * DM + c0;
  f32x4 acc[4];
#pragma unroll
  for (int i = 0; i < 4; ++i) acc[i] = f32x4{0.f, 0.f, 0.f, 0.f};

  bf16x8 ar[4], br[4];
#pragma unroll
  for (int j = 0; j < 4; ++j) {
    ar[j] = *reinterpret_cast<const bf16x8*>(ap + j * 8);
    br[j] = *reinterpret_cast<const bf16x8*>(bp + j * 8);
  }
  for (int k0 = 0; k0 < DM; k0 += 128) {
    __syncthreads();
#pragma unroll
    for (int j = 0; j < 4; ++j) {
      *reinterpret_cast<bf16x8*>(&At[r][c0 + j * 8]) = ar[j];
      *reinterpret_cast<bf16x8*>(&Bts[r][c0 + j * 8]) = br[j];
    }
    if (k0 + 128 < DM) {
#pragma unroll
      for (int j = 0; j < 4; ++j) {
        ar[j] = *reinterpret_cast<const bf16x8*>(ap + k0 + 128 + j * 8);
        br[j] = *reinterpret_cast<const bf16x8*>(bp + k0 + 128 + j * 8);
      }
    }
    __syncthreads();
#pragma unroll
    for (int kk = 0; kk < 4; ++kk) {
      const bf16x8 af = *reinterpret_cast<const bf16x8*>(&At[wv * 16 + m][kk * 32 + q * 8]);
#pragma unroll
      for (int c = 0; c < 4; ++c) {
        const bf16x8 bf = *reinterpret_cast<const bf16x8*>(&Bts[c * 16 + m][kk * 32 + q * 8]);
        acc[c] = MFMA16(af, bf, acc[c]);
      }
    }
  }
#pragma unroll
  for (int r2 = 0; r2 < 4; ++r2)
#pragma unroll
    for (int c = 0; c < 4; ++c)
      C[(long)(m0 + wv * 16 + q * 4 + r2) * QKVN + n0 + c * 16 + m] = (__bf16)acc[c][r2];
}

// ---------------------------------------------------------------------------
// K2: kf-features with SWAPPED operands (round 10).
// Compute D[proj][l] = mfma(projT_frag, x_frag) so each thread owns one full
// l-row: softmax reduction = 2 shfl_xor (masks 16/32), and output packs as
// bf16x8 per c. Permuted feature layout (consistent with flash's qf):
//   col' = c*32 + q*8 + r + 4*neg,  p = c*16 + q*4 + r.
// Any fixed permutation of the 512 feature cols is contraction-invariant.
// projT B-staging dropped: fragments read directly from global (L1-resident).
// ---------------------------------------------------------------------------
__global__ __launch_bounds__(256) void features_mfma(const __bf16* __restrict__ qkv,
                                                     const __bf16* __restrict__ projT,
                                                     const __bf16* __restrict__ pi0,
                                                     const __bf16* __restrict__ pi1,
                                                     __bf16* __restrict__ kf) {
  const int l0 = blockIdx.x * 64;
  const int bh = blockIdx.y;
  const int h = bh & 7, b = bh >> 3;
  const int tid = threadIdx.x, lane = tid & 63, wv = tid >> 6;
  const int m = lane & 15, q = lane >> 4;
  __shared__ __bf16 As[2][64][72];   // k1 / k2 tiles: 64 l-rows x 64 d

  {
    const int r = tid >> 2, c0 = (tid & 3) * 16;
    const __bf16* ap = qkv + (long)((l0 + r) * B_SZ + b) * QKVN + h * 256 + 64 + c0;
#pragma unroll
    for (int t2 = 0; t2 < 2; ++t2) {
      *reinterpret_cast<bf16x8*>(&As[t2][r][c0]) =
          *reinterpret_cast<const bf16x8*>(ap + t2 * 64);
      *reinterpret_cast<bf16x8*>(&As[t2][r][c0 + 8]) =
          *reinterpret_cast<const bf16x8*>(ap + t2 * 64 + 8);
    }
  }
  const int l = l0 + wv * 16 + m;          // this thread's sequence row
  const float p0w = (float)pi0[h * 256 + l];
  const float p1w = (float)pi1[h * 256 + l];
  const float SQ = 0.35355339f;            // 64^-0.25
  const float SK2 = 0.24748737f;           // 0.7 * 64^-0.25
  __syncthreads();

  f32x4 acc1[16], acc2[16];
#pragma unroll
  for (int c = 0; c < 16; ++c) {
    acc1[c] = f32x4{0.f, 0.f, 0.f, 0.f};
    acc2[c] = f32x4{0.f, 0.f, 0.f, 0.f};
  }
#pragma unroll
  for (int kk = 0; kk < 2; ++kk) {
    const bf16x8 x1 = *reinterpret_cast<const bf16x8*>(&As[0][wv * 16 + m][kk * 32 + q * 8]);
    const bf16x8 x2 = *reinterpret_cast<const bf16x8*>(&As[1][wv * 16 + m][kk * 32 + q * 8]);
#pragma unroll
    for (int c = 0; c < 16; ++c) {
      const bf16x8 wf =
          *reinterpret_cast<const bf16x8*>(projT + (long)(c * 16 + m) * 64 + kk * 32 + q * 8);
      acc1[c] = MFMA16(wf, x1, acc1[c]);   // acc[c][r] = [l=wv*16+m][p=c*16+q*4+r]
      acc2[c] = MFMA16(wf, x2, acc2[c]);
    }
  }
  float mx1 = 0.f, mx2 = 0.f;
#pragma unroll
  for (int c = 0; c < 16; ++c)
#pragma unroll
    for (int r = 0; r < 4; ++r) {
      mx1 = fmaxf(mx1, fabsf(acc1[c][r] * SQ));
      mx2 = fmaxf(mx2, fabsf(acc2[c][r] * SK2));
    }
  mx1 = fmaxf(mx1, __shfl_xor(mx1, 16)); mx1 = fmaxf(mx1, __shfl_xor(mx1, 32));
  mx2 = fmaxf(mx2, __shfl_xor(mx2, 16)); mx2 = fmaxf(mx2, __shfl_xor(mx2, 32));
  const float C21 = __expf(-2.f * mx1);
  const float C22 = __expf(-2.f * mx2);
  float sm1 = 0.f, sm2 = 0.f;
#pragma unroll
  for (int c = 0; c < 16; ++c)
#pragma unroll
    for (int r = 0; r < 4; ++r) {
      const float e11 = __expf(acc1[c][r] * SQ - mx1);
      const float e12 = __expf(acc2[c][r] * SK2 - mx2);
      sm1 += e11 + C21 * __builtin_amdgcn_rcpf(e11);
      sm2 += e12 + C22 * __builtin_amdgcn_rcpf(e12);
      acc1[c][r] = e11;
      acc2[c][r] = e12;
    }
  sm1 += __shfl_xor(sm1, 16); sm1 += __shfl_xor(sm1, 32);
  sm2 += __shfl_xor(sm2, 16); sm2 += __shfl_xor(sm2, 32);
  const float w1 = p0w * __builtin_amdgcn_rcpf(sm1);
  const float w2 = p1w * __builtin_amdgcn_rcpf(sm2);
  const float K1 = C21 * w1, K2 = C22 * w2;
  __bf16* op = kf + ((long)bh * 256 + l) * FD;
#pragma unroll
  for (int c = 0; c < 16; ++c) {
    bf16x8 v;
#pragma unroll
    for (int r = 0; r < 4; ++r) {
      v[r]     = (__bf16)(w1 * acc1[c][r] + w2 * acc2[c][r]);
      v[4 + r] = (__bf16)(K1 * __builtin_amdgcn_rcpf(acc1[c][r]) +
                          K2 * __builtin_amdgcn_rcpf(acc2[c][r]));
    }
    *reinterpret_cast<bf16x8*>(op + c * 32 + q * 8) = v;
  }
}

// ---------------------------------------------------------------------------
// K2b: pack V transposed per head: vt[bh][d][s] (validated).
// ---------------------------------------------------------------------------
__global__ __launch_bounds__(256) void vpack(const __bf16* __restrict__ qkv,
                                             __bf16* __restrict__ vt) {
  const int s0 = blockIdx.x * 64;
  const int bh = blockIdx.y;
  const int h = bh & 7, b = bh >> 3;
  __shared__ __bf16 T[64][72];
  const int tid = threadIdx.x;
  {
    const int s = tid >> 2, d0 = (tid & 3) * 16;
    const __bf16* vp = qkv + ((long)((s0 + s) * B_SZ + b)) * QKVN + h * 256 + 192 + d0;
#pragma unroll
    for (int j = 0; j < 16; ++j) T[d0 + j][s] = vp[j];
  }
  __syncthreads();
  {
    const int d = tid >> 2, sc = (tid & 3) * 16;
    __bf16* op = vt + ((long)bh * 64 + d) * 256 + s0 + sc;
    *reinterpret_cast<bf16x8*>(op)     = *reinterpret_cast<const bf16x8*>(&T[d][sc]);
    *reinterpret_cast<bf16x8*>(op + 8) = *reinterpret_cast<const bf16x8*>(&T[d][sc + 8]);
  }
}

// ---------------------------------------------------------------------------
// K3: flash, round 10: TILE-PER-BLOCK (grid 1024 = 4 tiles x 256 bh).
// - XCD-swizzled block id: the 4 tile-blocks of one bh share an XCD's L2,
//   so kf tile re-reads (tile t read by blocks t..3) mostly hit L2.
// - q-feature phase with SWAPPED operands: each thread owns one l-row; the
//   A-fragments qT[16] come straight out of the accumulators — the old
//   Qtmp LDS roundtrip (17.4 KB + 8 barriers) and the Bs projT staging
//   (36.9 KB) are gone. Union LDS 63.5 KB -> 37.25 KB (3-4 blocks/CU).
// - main loop: validated chunk structure, single tile (qB path dropped).
// ---------------------------------------------------------------------------
union FlashSmem {
  struct { __bf16 As[64][72]; } f;                                     //  9.2 KB
  struct { __bf16 Kc[64][136]; __bf16 Vt[80][72]; __bf16 Pt[64][72]; } mn;  // 38.1 KB
};

__global__ __launch_bounds__(256, 3) void flash_mfma(const __bf16* __restrict__ qkv,
                                                     const __bf16* __restrict__ projT,
                                                     const __bf16* __restrict__ kf,
                                                     const __bf16* __restrict__ vt,
                                                     __bf16* __restrict__ att) {
  const int id = blockIdx.x;
  // id -> (bh, t): tiles of one bh land 8 apart => same XCD under %8 round-robin
  const int bh = (id & 7) * 32 + (id >> 5);
  const int t  = (id >> 3) & 3;
  const int h = bh & 7, b = bh >> 3;
  const int tid = threadIdx.x, lane = tid & 63, wv = tid >> 6;
  const int m = lane & 15, q = lane >> 4;
  __shared__ FlashSmem S;

  // main-loop pointers; issue st=0/ch=0 prefetch early (hides under features)
  const int vrow = tid >> 2, vc0 = (tid & 3) * 16;
  const int krow = tid >> 2, kc0 = (tid & 3) * 32;
  const __bf16* vbase = vt + ((long)bh * 64 + vrow) * 256 + vc0;
  const __bf16* kbase = kf + ((long)(bh * 256 + krow)) * FD + kc0;
  bf16x8 vr0 = *reinterpret_cast<const bf16x8*>(vbase);
  bf16x8 vr1 = *reinterpret_cast<const bf16x8*>(vbase + 8);
  bf16x8 kr[4];
#pragma unroll
  for (int j = 0; j < 4; ++j) kr[j] = *reinterpret_cast<const bf16x8*>(kbase + j * 8);

  // ---------------- feature phase: build qT[16] in-register ----------------
  const float SQ = 0.35355339f;          // 64^-0.25
  {
    const int r = tid >> 2, c0 = (tid & 3) * 16;
    const __bf16* ap = qkv + (long)((t * 64 + r) * B_SZ + b) * QKVN + h * 256 + c0;
    *reinterpret_cast<bf16x8*>(&S.f.As[r][c0])     = *reinterpret_cast<const bf16x8*>(ap);
    *reinterpret_cast<bf16x8*>(&S.f.As[r][c0 + 8]) = *reinterpret_cast<const bf16x8*>(ap + 8);
  }
  __syncthreads();
  f32x4 acc[16];
#pragma unroll
  for (int c = 0; c < 16; ++c) acc[c] = f32x4{0.f, 0.f, 0.f, 0.f};
#pragma unroll
  for (int kk = 0; kk < 2; ++kk) {
    const bf16x8 xf = *reinterpret_cast<const bf16x8*>(&S.f.As[wv * 16 + m][kk * 32 + q * 8]);
#pragma unroll
    for (int c = 0; c < 16; ++c) {
      const bf16x8 wf =
          *reinterpret_cast<const bf16x8*>(projT + (long)(c * 16 + m) * 64 + kk * 32 + q * 8);
      acc[c] = MFMA16(wf, xf, acc[c]);   // acc[c][r] = qf-pre[l=wv*16+m][p=c*16+q*4+r]
    }
  }
  float mx = 0.f;
#pragma unroll
  for (int c = 0; c < 16; ++c)
#pragma unroll
    for (int r = 0; r < 4; ++r) mx = fmaxf(mx, fabsf(acc[c][r] * SQ));
  mx = fmaxf(mx, __shfl_xor(mx, 16));
  mx = fmaxf(mx, __shfl_xor(mx, 32));
  const float C2 = __expf(-2.f * mx);
  float sm = 0.f;
#pragma unroll
  for (int c = 0; c < 16; ++c)
#pragma unroll
    for (int r = 0; r < 4; ++r) {
      const float e1 = __expf(acc[c][r] * SQ - mx);
      sm += e1 + C2 * __builtin_amdgcn_rcpf(e1);
      acc[c][r] = e1;
    }
  sm += __shfl_xor(sm, 16);
  sm += __shfl_xor(sm, 32);
  const float inv = __builtin_amdgcn_rcpf(sm);
  const float K2 = C2 * inv;
  bf16x8 qT[16];                         // A-frags, col' = c*32 + q*8 + (r + 4*neg)
#pragma unroll
  for (int c = 0; c < 16; ++c) {
    bf16x8 v;
#pragma unroll
    for (int r = 0; r < 4; ++r) {
      v[r]     = (__bf16)(acc[c][r] * inv);
      v[4 + r] = (__bf16)(K2 * __builtin_amdgcn_rcpf(acc[c][r]));
    }
    qT[c] = v;
  }
  __syncthreads();                       // union switch: As region -> Kc

  // ---------------- main loop (single tile) ----------------
  f32x4 o[5];
#pragma unroll
  for (int i = 0; i < 5; ++i) o[i] = f32x4{0.f, 0.f, 0.f, 0.f};

  if (tid < 64) S.mn.Vt[64][tid] = (__bf16)1.0f;
  for (int z = tid; z < 15 * 64; z += 256) S.mn.Vt[65 + (z >> 6)][z & 63] = (__bf16)0.f;

  for (int st = 0; st <= t; ++st) {
    f32x4 s[4];
#pragma unroll
    for (int i = 0; i < 4; ++i) s[i] = f32x4{0.f, 0.f, 0.f, 0.f};
#pragma unroll
    for (int ch = 0; ch < 4; ++ch) {
      __syncthreads();
      if (ch == 0) {
        *reinterpret_cast<bf16x8*>(&S.mn.Vt[vrow][vc0])     = vr0;
        *reinterpret_cast<bf16x8*>(&S.mn.Vt[vrow][vc0 + 8]) = vr1;
      }
#pragma unroll
      for (int j = 0; j < 4; ++j)
        *reinterpret_cast<bf16x8*>(&S.mn.Kc[krow][kc0 + j * 8]) = kr[j];
      if (ch < 3) {
        const __bf16* kp = kbase + (long)st * 64 * FD + (ch + 1) * 128;
#pragma unroll
        for (int j = 0; j < 4; ++j) kr[j] = *reinterpret_cast<const bf16x8*>(kp + j * 8);
      } else if (st < t) {
        const __bf16* kp = kbase + (long)(st + 1) * 64 * FD;
#pragma unroll
        for (int j = 0; j < 4; ++j) kr[j] = *reinterpret_cast<const bf16x8*>(kp + j * 8);
        vr0 = *reinterpret_cast<const bf16x8*>(vbase + (st + 1) * 64);
        vr1 = *reinterpret_cast<const bf16x8*>(vbase + (st + 1) * 64 + 8);
      }
      __syncthreads();
#pragma unroll
      for (int kk = 0; kk < 4; ++kk) {
#pragma unroll
        for (int c = 0; c < 4; ++c) {
          const bf16x8 bf = *reinterpret_cast<const bf16x8*>(&S.mn.Kc[c * 16 + m][kk * 32 + q * 8]);
          s[c] = MFMA16(qT[ch * 4 + kk], bf, s[c]);
        }
      }
    }
    {
      const bool mask = (st == t);
#pragma unroll
      for (int c = 0; c < 4; ++c)
#pragma unroll
        for (int r = 0; r < 4; ++r) {
          const int row = wv * 16 + q * 4 + r, col = c * 16 + m;
          S.mn.Pt[row][col] = (__bf16)((mask && col > row) ? 0.f : s[c][r]);
        }
#pragma unroll
      for (int kk = 0; kk < 2; ++kk) {
        const bf16x8 pf = *reinterpret_cast<const bf16x8*>(&S.mn.Pt[wv * 16 + m][kk * 32 + q * 8]);
#pragma unroll
        for (int c = 0; c < 5; ++c) {
          const bf16x8 vf = *reinterpret_cast<const bf16x8*>(&S.mn.Vt[c * 16 + m][kk * 32 + q * 8]);
          o[c] = MFMA16(pf, vf, o[c]);
        }
      }
    }
  }
#pragma unroll
  for (int r = 0; r < 4; ++r) {
    const float den = __shfl(o[4][r], (lane & 48));
    const float invd = 0.125f / (den + 1e-5f);           // SCALE=64^-0.5, EPS
    const int row = t * 64 + wv * 16 + q * 4 + r;
#pragma unroll
    for (int c = 0; c < 4; ++c)
      att[((long)(row * B_SZ + b)) * DM + h * DH + c * 16 + m] = (__bf16)(o[c][r] * invd);
  }
}

// ---------------------------------------------------------------------------
// K4: xrow = hb + att @ w_o (f32 out), MFMA with register prefetch.
// ---------------------------------------------------------------------------
__global__ __launch_bounds__(256) void gemm_att_wo(const __bf16* __restrict__ A,
                                                   const __bf16* __restrict__ Bt,
                                                   const __bf16* __restrict__ hb,
                                                   float* __restrict__ xrow) {
  __shared__ __bf16 At[64][136];
  __shared__ __bf16 Bts[64][136];
  const int n0 = blockIdx.x * 64, m0 = blockIdx.y * 64;
  const int tid = threadIdx.x, lane = tid & 63, wv = tid >> 6;
  const int m = lane & 15, q = lane >> 4;
  const int r = tid >> 2, c0 = (tid & 3) * 32;
  const __bf16* ap = A + (long)(m0 + r) * DM + c0;
  const __bf16* bp = Bt + (long)(n0 + r) * DM + c0;
  f32x4 acc[4];
#pragma unroll
  for (int i = 0; i < 4; ++i) acc[i] = f32x4{0.f, 0.f, 0.f, 0.f};

  bf16x8 ar[4], br[4];
#pragma unroll
  for (int j = 0; j < 4; ++j) {
    ar[j] = *reinterpret_cast<const bf16x8*>(ap + j * 8);
    br[j] = *reinterpret_cast<const bf16x8*>(bp + j * 8);
  }
  for (int k0 = 0; k0 < DM; k0 += 128) {
    __syncthreads();
#pragma unroll
    for (int j = 0; j < 4; ++j) {
      *reinterpret_cast<bf16x8*>(&At[r][c0 + j * 8]) = ar[j];
      *reinterpret_cast<bf16x8*>(&Bts[r][c0 + j * 8]) = br[j];
    }
    if (k0 + 128 < DM) {
#pragma unroll
      for (int j = 0; j < 4; ++j) {
        ar[j] = *reinterpret_cast<const bf16x8*>(ap + k0 + 128 + j * 8);
        br[j] = *reinterpret_cast<const bf16x8*>(bp + k0 + 128 + j * 8);
      }
    }
    __syncthreads();
#pragma unroll
    for (int kk = 0; kk < 4; ++kk) {
      const bf16x8 af = *reinterpret_cast<const bf16x8*>(&At[wv * 16 + m][kk * 32 + q * 8]);
#pragma unroll
      for (int c = 0; c < 4; ++c) {
        const bf16x8 bf = *reinterpret_cast<const bf16x8*>(&Bts[c * 16 + m][kk * 32 + q * 8]);
        acc[c] = MFMA16(af, bf, acc[c]);
      }
    }
  }
#pragma unroll
  for (int r2 = 0; r2 < 4; ++r2)
#pragma unroll
    for (int c = 0; c < 4; ++c) {
      const long row = m0 + wv * 16 + q * 4 + r2;
      const long col = n0 + c * 16 + m;
      xrow[row * DM + col] = acc[c][r2] + (float)hb[row * DM + col];
    }
}

// ---------------------------------------------------------------------------
// K5: LayerNorm rows of xrow -> out (validated rounds 4-8).
// ---------------------------------------------------------------------------
__global__ __launch_bounds__(256) void ln_out(const float* __restrict__ xrow,
                                              const __bf16* __restrict__ gamma,
                                              const __bf16* __restrict__ beta,
                                              const int* __restrict__ flag,
                                              void* __restrict__ out) {
  const int f32 = flag[0];
  const int r = blockIdx.x;
  const int tid = threadIdx.x;
  __shared__ float red[256];
  const float x0 = xrow[(long)r * DM + tid];
  const float x1 = xrow[(long)r * DM + tid + 256];

  red[tid] = x0 + x1; __syncthreads();
  for (int s = 128; s > 0; s >>= 1) { if (tid < s) red[tid] += red[tid + s]; __syncthreads(); }
  const float mu = red[0] * (1.f / 512.f); __syncthreads();
  red[tid] = x0 * x0 + x1 * x1; __syncthreads();
  for (int s = 128; s > 0; s >>= 1) { if (tid < s) red[tid] += red[tid + s]; __syncthreads(); }
  const float var = red[0] * (1.f / 512.f) - mu * mu; __syncthreads();
  const float rstd = rsqrtf(var + 1e-5f);

  stmix(out, (long)r * DM + tid,
        (x0 - mu) * rstd * (float)gamma[tid] + (float)beta[tid], f32);
  stmix(out, (long)r * DM + tid + 256,
        (x1 - mu) * rstd * (float)gamma[tid + 256] + (float)beta[tid + 256], f32);
}

// ---------------------------------------------------------------------------
extern "C" void kernel_launch(void* const* d_in, const int* in_sizes, int n_in,
                              void* d_out, int out_size, void* d_ws, size_t ws_size,
                              hipStream_t stream) {
  (void)in_sizes; (void)n_in; (void)out_size; (void)ws_size;
  char* ws = (char*)d_ws;
  __bf16* qkv   = (__bf16*)ws;
  int*    flag  = (int*)(ws + 33554432);
  __bf16* wt    = (__bf16*)(ws + 33554688);
  __bf16* wot   = (__bf16*)(ws + 35651840);
  __bf16* att   = (__bf16*)(ws + 36176128);
  __bf16* vt    = (__bf16*)(ws + 44564736);
  __bf16* hb    = (__bf16*)(ws + 52953344);
  __bf16* projT = (__bf16*)(ws + 61341952);
  __bf16* pi0b  = (__bf16*)(ws + 61374720);
  __bf16* pi1b  = (__bf16*)(ws + 61378816);
  __bf16* gamb  = (__bf16*)(ws + 61382912);
  __bf16* betb  = (__bf16*)(ws + 61383936);
  __bf16* kf    = (__bf16*)(ws + 128493824);
  float*  xrow  = (float*)(ws + 61384960);   // free region (old qf slot)

  prep<<<PREP_BLOCKS, 256, 0, stream>>>(d_in[0], d_in[1], d_in[2], d_in[7],
                                        d_in[5], d_in[6], d_in[3], d_in[4],
                                        flag, hb, wt, wot, projT,
                                        pi0b, pi1b, gamb, betb);
  gemm_h_wqkv<<<dim3(32, 128), 256, 0, stream>>>(hb, wt, qkv);
  vpack<<<dim3(4, 256), 256, 0, stream>>>(qkv, vt);
  features_mfma<<<dim3(4, 256), 256, 0, stream>>>(qkv, projT, pi0b, pi1b, kf);
  flash_mfma<<<dim3(1024), 256, 0, stream>>>(qkv, projT, kf, vt, att);
  gemm_att_wo<<<dim3(8, 128), 256, 0, stream>>>(att, wot, hb, xrow);
  ln_out<<<dim3(ROWS), 256, 0, stream>>>(xrow, gamb, betb, flag, d_out);
}